// Round 1
// baseline (414.544 us; speedup 1.0000x reference)
//
#include <hip/hip_runtime.h>

// Problem constants (fixed by reference): x (1,64,8,56,56), offset (1,648,8,56,56),
// weight (64,64,3,3,3), stride=1, pad=1, cpg=8.
namespace {
constexpr int D = 8, H = 56, W = 56;
constexpr int HW = H * W;
constexpr int C = 64, G = 8, CPG = 8;
constexpr int KV = 27;
constexpr int N = D * H * W;   // 25088
constexpr int O = 64;
constexpr int NT = 64;         // spatial tile per block
}

// x [C][N] -> xt [N][C]  (channels-last so a trilinear corner reads 8 contiguous floats)
__global__ __launch_bounds__(256) void xpose_kernel(const float* __restrict__ x,
                                                    float* __restrict__ xt) {
    __shared__ float tile[64][65];
    const int tid = threadIdx.x;
    const int n0 = blockIdx.x * 64;
#pragma unroll
    for (int i = 0; i < 16; ++i) {
        int e = i * 256 + tid;
        int c = e >> 6, nl = e & 63;
        tile[c][nl] = x[c * N + n0 + nl];       // coalesced read along n
    }
    __syncthreads();
#pragma unroll
    for (int i = 0; i < 16; ++i) {
        int e = i * 256 + tid;
        int nl = e >> 6, c = e & 63;
        xt[(n0 + nl) * C + c] = tile[c][nl];    // coalesced write along c
    }
}

// weight [O][C][KV] -> wt [KV][C][O]  (per-kv slice becomes a flat 16KB copy)
__global__ __launch_bounds__(256) void wpose_kernel(const float* __restrict__ w,
                                                    float* __restrict__ wt) {
    int idx = blockIdx.x * 256 + threadIdx.x;
    if (idx >= O * C * KV) return;
    int o = idx & 63;
    int c = (idx >> 6) & 63;
    int kv = idx >> 12;
    wt[idx] = w[(o * C + c) * KV + kv];
}

__global__ __launch_bounds__(256) void dconv_kernel(const float* __restrict__ offset,
                                                    const float* __restrict__ xt,
                                                    const float* __restrict__ wt,
                                                    float* __restrict__ out) {
    __shared__ float val_s[64][64];  // [c][nt]
    __shared__ float w_s[64][64];    // [c][o]
    const int tid = threadIdx.x;
    const int n0 = blockIdx.x * NT;
    const int ty = tid >> 4, tx = tid & 15;

    // Each thread owns 2 sampling tasks (g, nt); precompute the kv-invariant parts.
    int t_g[2], t_nt[2], t_zo[2], t_yo[2], t_xo[2], t_ob[2];
#pragma unroll
    for (int ph = 0; ph < 2; ++ph) {
        int task = ph * 256 + tid;
        int g = task >> 6;
        int nt = task & 63;
        int n = n0 + nt;
        int zo = n / HW;
        int rem = n - zo * HW;
        int yo = rem / W;
        int xo = rem - yo * W;
        t_g[ph] = g; t_nt[ph] = nt;
        t_zo[ph] = zo; t_yo[ph] = yo; t_xo[ph] = xo;
        t_ob[ph] = g * (KV * 3 * N) + n;
    }

    float acc[4][4] = {{0.f, 0.f, 0.f, 0.f}, {0.f, 0.f, 0.f, 0.f},
                       {0.f, 0.f, 0.f, 0.f}, {0.f, 0.f, 0.f, 0.f}};

    for (int kv = 0; kv < KV; ++kv) {
        const int kz = kv / 9;
        const int ky = (kv / 3) % 3;
        const int kx = kv % 3;

        // ---- sampling phase: fill val_s[c][nt] for this kv ----
#pragma unroll
        for (int ph = 0; ph < 2; ++ph) {
            const int g = t_g[ph];
            const int boff = t_ob[ph] + kv * (3 * N);
            float zc = (float)(t_zo[ph] + kz - 1) + offset[boff];
            float yc = (float)(t_yo[ph] + ky - 1) + offset[boff + N];
            float xc = (float)(t_xo[ph] + kx - 1) + offset[boff + 2 * N];
            float zf = floorf(zc), yf = floorf(yc), xf = floorf(xc);
            float dz = zc - zf, dy = yc - yf, dx = xc - xf;
            int z0 = (int)zf, y0 = (int)yf, x0 = (int)xf;
            float v0 = 0.f, v1 = 0.f, v2 = 0.f, v3 = 0.f;
            float v4 = 0.f, v5 = 0.f, v6 = 0.f, v7 = 0.f;
#pragma unroll
            for (int cz = 0; cz < 2; ++cz) {
                int zi = z0 + cz;
                if (zi < 0 || zi >= D) continue;
                float wz = cz ? dz : 1.0f - dz;
#pragma unroll
                for (int cy = 0; cy < 2; ++cy) {
                    int yi = y0 + cy;
                    if (yi < 0 || yi >= H) continue;
                    float wy = cy ? dy : 1.0f - dy;
#pragma unroll
                    for (int cx = 0; cx < 2; ++cx) {
                        int xi = x0 + cx;
                        if (xi < 0 || xi >= W) continue;
                        float wc = wz * wy * (cx ? dx : 1.0f - dx);
                        const float* p = xt + ((zi * H + yi) * W + xi) * C + g * CPG;
                        float4 a = *(const float4*)p;
                        float4 b = *(const float4*)(p + 4);
                        v0 += wc * a.x; v1 += wc * a.y; v2 += wc * a.z; v3 += wc * a.w;
                        v4 += wc * b.x; v5 += wc * b.y; v6 += wc * b.z; v7 += wc * b.w;
                    }
                }
            }
            float* dstp = &val_s[g * CPG][0] + t_nt[ph];  // channel stride = 64 floats
            dstp[0 * 64] = v0; dstp[1 * 64] = v1; dstp[2 * 64] = v2; dstp[3 * 64] = v3;
            dstp[4 * 64] = v4; dstp[5 * 64] = v5; dstp[6 * 64] = v6; dstp[7 * 64] = v7;
        }

        // ---- stage weight slice wt[kv] (= [c][o], 16 KB) into LDS ----
        {
            const float4* src = (const float4*)(wt + kv * (C * O));
            float4* dst = (float4*)&w_s[0][0];
#pragma unroll
            for (int i = 0; i < 4; ++i) dst[i * 256 + tid] = src[i * 256 + tid];
        }
        __syncthreads();

        // ---- 64x64x64 FMA matmul: acc[o 4][n 4] += w_s[c][o] * val_s[c][n] ----
#pragma unroll 8
        for (int c = 0; c < C; ++c) {
            float4 wv = *(const float4*)&w_s[c][ty * 4];
            float4 vv = *(const float4*)&val_s[c][tx * 4];
            acc[0][0] += wv.x * vv.x; acc[0][1] += wv.x * vv.y; acc[0][2] += wv.x * vv.z; acc[0][3] += wv.x * vv.w;
            acc[1][0] += wv.y * vv.x; acc[1][1] += wv.y * vv.y; acc[1][2] += wv.y * vv.z; acc[1][3] += wv.y * vv.w;
            acc[2][0] += wv.z * vv.x; acc[2][1] += wv.z * vv.y; acc[2][2] += wv.z * vv.z; acc[2][3] += wv.z * vv.w;
            acc[3][0] += wv.w * vv.x; acc[3][1] += wv.w * vv.y; acc[3][2] += wv.w * vv.z; acc[3][3] += wv.w * vv.w;
        }
        __syncthreads();
    }

#pragma unroll
    for (int i = 0; i < 4; ++i) {
        int o = ty * 4 + i;
        float4 r;
        r.x = acc[i][0]; r.y = acc[i][1]; r.z = acc[i][2]; r.w = acc[i][3];
        *(float4*)&out[o * N + n0 + tx * 4] = r;
    }
}

extern "C" void kernel_launch(void* const* d_in, const int* in_sizes, int n_in,
                              void* d_out, int out_size, void* d_ws, size_t ws_size,
                              hipStream_t stream) {
    const float* x      = (const float*)d_in[0];
    const float* offset = (const float*)d_in[1];
    const float* weight = (const float*)d_in[2];
    float* out = (float*)d_out;

    float* xt = (float*)d_ws;            // N*C floats = 6.4 MB
    float* wt = xt + (size_t)N * C;      // KV*C*O floats = 0.44 MB

    xpose_kernel<<<N / 64, 256, 0, stream>>>(x, xt);
    wpose_kernel<<<(O * C * KV + 255) / 256, 256, 0, stream>>>(weight, wt);
    dconv_kernel<<<N / NT, 256, 0, stream>>>(offset, xt, wt, out);
}

// Round 2
// 218.399 us; speedup vs baseline: 1.8981x; 1.8981x over previous
//
#include <hip/hip_runtime.h>

// Problem constants: x (1,64,8,56,56), offset (1,648,8,56,56),
// weight (64,64,3,3,3), stride=1, pad=1, cpg=8.
namespace {
constexpr int D = 8, H = 56, W = 56;
constexpr int HW = H * W;
constexpr int C = 64, G = 8, CPG = 8;
constexpr int KV = 27;
constexpr int KVC = 9;           // taps per chunk
constexpr int NCHUNK = 3;        // kv split factor
constexpr int N = D * H * W;     // 25088
constexpr int O = 64;
constexpr int NT = 64;           // spatial tile per block
constexpr int NTILES = N / NT;   // 392
}

typedef short bf16x8 __attribute__((ext_vector_type(8)));
typedef float f32x4 __attribute__((ext_vector_type(4)));

// round-to-nearest-even f32 -> bf16, packed pair (a low, b high)
__device__ inline unsigned bfpack(float a, float b) {
    unsigned ua = __float_as_uint(a); ua = (ua + 0x7fffu + ((ua >> 16) & 1u)) >> 16;
    unsigned ub = __float_as_uint(b); ub = (ub + 0x7fffu + ((ub >> 16) & 1u));
    return ua | (ub & 0xffff0000u);
}
__device__ inline float blo(unsigned d) { return __uint_as_float(d << 16); }
__device__ inline float bhi(unsigned d) { return __uint_as_float(d & 0xffff0000u); }

// x [C][N] fp32 -> xt [g][z][y][x][cpg] bf16 (one 16B vector per spatial point per group)
__global__ __launch_bounds__(256) void xpose_kernel(const float* __restrict__ x,
                                                    ushort* __restrict__ xt) {
    const int b = blockIdx.x;
    const int g = b / 98;                       // 98 blocks per group (98*256 = 25088)
    const int n = (b % 98) * 256 + threadIdx.x;
    float v[8];
#pragma unroll
    for (int cc = 0; cc < 8; ++cc) v[cc] = x[(size_t)(g * CPG + cc) * N + n];
    uint4 p;
    p.x = bfpack(v[0], v[1]); p.y = bfpack(v[2], v[3]);
    p.z = bfpack(v[4], v[5]); p.w = bfpack(v[6], v[7]);
    *(uint4*)(xt + ((size_t)g * N + n) * CPG) = p;
}

// weight [O][C][KV] fp32 -> wt [kv][o][c] bf16 with the LDS XOR-swizzle pre-applied,
// so a linear 8KB copy into LDS lands in swizzled [o][c] layout.
__global__ __launch_bounds__(256) void wpose_kernel(const float* __restrict__ w,
                                                    ushort* __restrict__ wt) {
    int idx = blockIdx.x * 256 + threadIdx.x;
    if (idx >= O * C * KV) return;
    int kv = idx % 27;
    int t = idx / 27;
    int c = t & 63;
    int o = t >> 6;
    unsigned u = __float_as_uint(w[idx]);
    u = (u + 0x7fffu + ((u >> 16) & 1u)) >> 16;
    int byte = ((o * 128 + (c & ~7) * 2) ^ ((o & 7) << 4)) + (c & 7) * 2;
    *(ushort*)((char*)wt + (size_t)kv * 8192 + byte) = (ushort)u;
}

__global__ __launch_bounds__(256) void dconv_kernel(const float* __restrict__ offset,
                                                    const ushort* __restrict__ xt,
                                                    const ushort* __restrict__ wt,
                                                    float* __restrict__ out) {
    __shared__ ushort val_s[64 * 64];  // [n][c] bf16, XOR-swizzled rows (8 KB)
    __shared__ ushort w_s[64 * 64];    // [o][c] bf16, XOR-swizzled rows (8 KB)
    const int tid = threadIdx.x;
    const int tile = blockIdx.x % NTILES;
    const int chunk = blockIdx.x / NTILES;
    const int n0 = tile * NT;
    const int kv0 = chunk * KVC;

    // 2 sampling tasks per thread: task = (g, nl). Precompute kv-invariant parts.
    int t_g[2], t_nl[2], t_zo[2], t_yo[2], t_xo[2];
    size_t t_ob[2];
#pragma unroll
    for (int ph = 0; ph < 2; ++ph) {
        int task = ph * 256 + tid;
        int g = task >> 6, nl = task & 63;
        int n = n0 + nl;
        int zo = n / HW, rem = n - zo * HW;
        int yo = rem / W, xo = rem - yo * W;
        t_g[ph] = g; t_nl[ph] = nl;
        t_zo[ph] = zo; t_yo[ph] = yo; t_xo[ph] = xo;
        t_ob[ph] = (size_t)g * KV * 3 * N + n;
    }

    const int lane = tid & 63;
    const int wv = tid >> 6;
    const int nq = wv * 16 + (lane & 15);  // this wave's n column (local)

    f32x4 acc[4];
#pragma unroll
    for (int i = 0; i < 4; ++i) acc[i] = (f32x4){0.f, 0.f, 0.f, 0.f};

    for (int kvi = 0; kvi < KVC; ++kvi) {
        const int kv = kv0 + kvi;
        const int kz = kv / 9, ky = (kv / 3) % 3, kx = kv % 3;

        // ---- sampling: fill val_s for this kv ----
#pragma unroll
        for (int ph = 0; ph < 2; ++ph) {
            const int g = t_g[ph];
            const float* ob = offset + t_ob[ph] + (size_t)kv * 3 * N;
            float zc = (float)(t_zo[ph] + kz - 1) + ob[0];
            float yc = (float)(t_yo[ph] + ky - 1) + ob[(size_t)N];
            float xc = (float)(t_xo[ph] + kx - 1) + ob[(size_t)2 * N];
            float zf = floorf(zc), yf = floorf(yc), xf = floorf(xc);
            float dz = zc - zf, dy = yc - yf, dx = xc - xf;
            int z0 = (int)zf, y0 = (int)yf, x0 = (int)xf;
            float v0 = 0.f, v1 = 0.f, v2 = 0.f, v3 = 0.f;
            float v4 = 0.f, v5 = 0.f, v6 = 0.f, v7 = 0.f;
            const ushort* xg = xt + (size_t)g * N * CPG;
#pragma unroll
            for (int cz = 0; cz < 2; ++cz) {
                int zi = z0 + cz;
                if (zi < 0 || zi >= D) continue;
                float wz = cz ? dz : 1.0f - dz;
#pragma unroll
                for (int cy = 0; cy < 2; ++cy) {
                    int yi = y0 + cy;
                    if (yi < 0 || yi >= H) continue;
                    float wy = wz * (cy ? dy : 1.0f - dy);
#pragma unroll
                    for (int cx = 0; cx < 2; ++cx) {
                        int xi = x0 + cx;
                        if (xi < 0 || xi >= W) continue;
                        float wc = wy * (cx ? dx : 1.0f - dx);
                        uint4 d = *(const uint4*)(xg + (size_t)((zi * H + yi) * W + xi) * CPG);
                        v0 += wc * blo(d.x); v1 += wc * bhi(d.x);
                        v2 += wc * blo(d.y); v3 += wc * bhi(d.y);
                        v4 += wc * blo(d.z); v5 += wc * bhi(d.z);
                        v6 += wc * blo(d.w); v7 += wc * bhi(d.w);
                    }
                }
            }
            uint4 p;
            p.x = bfpack(v0, v1); p.y = bfpack(v2, v3);
            p.z = bfpack(v4, v5); p.w = bfpack(v6, v7);
            int byte = (t_nl[ph] * 128 + g * 16) ^ ((t_nl[ph] & 7) << 4);
            *(uint4*)((char*)val_s + byte) = p;
        }

        // ---- stage this kv's weight slice (pre-swizzled, linear 8 KB) ----
        {
            const uint4* src = (const uint4*)(wt + (size_t)kv * 4096);
            uint4* dst = (uint4*)w_s;
            dst[tid] = src[tid];
            dst[tid + 256] = src[tid + 256];
        }
        __syncthreads();

        // ---- MFMA: acc[o 64][n 16/wave] += w[o][c] * val[c][n], K=64 ----
#pragma unroll
        for (int ks = 0; ks < 2; ++ks) {
            int c2 = (ks * 32 + (lane >> 4) * 8) * 2;  // byte offset of k-group in row
            int bbyte = (nq * 128 + c2) ^ ((nq & 7) << 4);
            bf16x8 bfrag = *(const bf16x8*)((const char*)val_s + bbyte);
#pragma unroll
            for (int of = 0; of < 4; ++of) {
                int orow = of * 16 + (lane & 15);
                int abyte = (orow * 128 + c2) ^ ((orow & 7) << 4);
                bf16x8 afrag = *(const bf16x8*)((const char*)w_s + abyte);
                acc[of] = __builtin_amdgcn_mfma_f32_16x16x32_bf16(afrag, bfrag, acc[of], 0, 0, 0);
            }
        }
        __syncthreads();
    }

    // ---- epilogue: accumulate partial (this kv-chunk) into out ----
#pragma unroll
    for (int of = 0; of < 4; ++of) {
#pragma unroll
        for (int r = 0; r < 4; ++r) {
            int o = of * 16 + (lane >> 4) * 4 + r;
            atomicAdd(&out[(size_t)o * N + n0 + nq], acc[of][r]);
        }
    }
}

extern "C" void kernel_launch(void* const* d_in, const int* in_sizes, int n_in,
                              void* d_out, int out_size, void* d_ws, size_t ws_size,
                              hipStream_t stream) {
    const float* x      = (const float*)d_in[0];
    const float* offset = (const float*)d_in[1];
    const float* weight = (const float*)d_in[2];
    float* out = (float*)d_out;

    ushort* xt = (ushort*)d_ws;                    // G*N*CPG bf16 = 3.2 MB
    ushort* wt = xt + (size_t)G * N * CPG;         // KV*O*C bf16 = 221 KB

    hipMemsetAsync(d_out, 0, (size_t)out_size * sizeof(float), stream);
    xpose_kernel<<<G * (N / 256), 256, 0, stream>>>(x, xt);
    wpose_kernel<<<(O * C * KV + 255) / 256, 256, 0, stream>>>(weight, wt);
    dconv_kernel<<<NTILES * NCHUNK, 256, 0, stream>>>(offset, xt, wt, out);
}